// Round 5
// baseline (100.003 us; speedup 1.0000x reference)
//
#include <hip/hip_runtime.h>

typedef unsigned short ushort_t;
typedef __attribute__((ext_vector_type(8))) __bf16 bf16x8;
typedef __attribute__((ext_vector_type(4))) float f32x4;
typedef __attribute__((ext_vector_type(4))) unsigned int u32x4;
typedef __attribute__((ext_vector_type(8))) unsigned short u16x8;

#define NQ 8192
#define NK 8192
#define DD 256
#define NSPLIT 16
#define SEG (NK / NSPLIT)   // 512 K-rows per split
#define KBLK 64             // K rows staged in LDS per tile
#define NT (SEG / KBLK)     // 8 tiles per block
#define LOG2E 1.4426950408889634f
#define LN2 0.6931471805599453f

using gptr_t = const __attribute__((address_space(1))) void*;
using lptr_t = __attribute__((address_space(3))) void*;

__device__ __forceinline__ float fexp2(float x) { return __builtin_amdgcn_exp2f(x); }
__device__ __forceinline__ float flog2(float x) { return __builtin_amdgcn_logf(x); }

// round-to-nearest-even fp32 -> bf16
__device__ __forceinline__ ushort_t f2bf(float f) {
  unsigned int u = __builtin_bit_cast(unsigned int, f);
  unsigned int r = 0x7FFFu + ((u >> 16) & 1u);
  return (ushort_t)((u + r) >> 16);
}

// ---------------------------------------------------------------------------
// Kernel 1: W [256x256] fp32 -> W^T bf16
// ---------------------------------------------------------------------------
__global__ __launch_bounds__(256) void transpose_w_kernel(
    const float* __restrict__ Wq, const float* __restrict__ Wk,
    ushort_t* __restrict__ WqT, ushort_t* __restrict__ WkT) {
  int idx = blockIdx.x * 256 + threadIdx.x;
  const float* W = (idx < 65536) ? Wq : Wk;
  ushort_t* WT = (idx < 65536) ? WqT : WkT;
  int e = idx & 65535;
  int d = e >> 8, n = e & 255;
  WT[n * 256 + d] = f2bf(W[d * 256 + n]);
}

// ---------------------------------------------------------------------------
// Kernel 2: projections  OUT_bf16[8192x256] = X_fp32 @ W  (via W^T rows)
// Q additionally scaled by log2(e) so the lse runs in base-2 (v_exp native).
// grid (128, 2, 2): y -> Q/K, z -> col-tile half.
// ---------------------------------------------------------------------------
__global__ __launch_bounds__(256) void proj_kernel(
    const float* __restrict__ xq, const float* __restrict__ xk,
    const ushort_t* __restrict__ WqT, const ushort_t* __restrict__ WkT,
    ushort_t* __restrict__ Qb, ushort_t* __restrict__ Kb) {
  const float* X = (blockIdx.y == 0) ? xq : xk;
  const ushort_t* WT = (blockIdx.y == 0) ? WqT : WkT;
  ushort_t* OUT = (blockIdx.y == 0) ? Qb : Kb;
  const float scale = (blockIdx.y == 0) ? LOG2E : 1.0f;

  const int tid = threadIdx.x;
  const int w = tid >> 6, lane = tid & 63;
  const int g = lane >> 4, c = lane & 15;
  const int rbase = blockIdx.x * 64 + w * 16;
  const int ctbase = blockIdx.z * 8;

  bf16x8 a[8];
#pragma unroll
  for (int kk = 0; kk < 8; ++kk) {
    const f32x4* px =
        reinterpret_cast<const f32x4*>(X + (size_t)(rbase + c) * DD + kk * 32 + g * 8);
    f32x4 x0 = px[0], x1 = px[1];
    u16x8 v;
#pragma unroll
    for (int j = 0; j < 4; ++j) { v[j] = f2bf(x0[j]); v[4 + j] = f2bf(x1[j]); }
    a[kk] = __builtin_bit_cast(bf16x8, v);
  }

#pragma unroll
  for (int ct0 = 0; ct0 < 8; ++ct0) {
    int ct = ctbase + ct0;
    f32x4 acc = {0.f, 0.f, 0.f, 0.f};
#pragma unroll
    for (int kk = 0; kk < 8; ++kk) {
      u32x4 bv = *reinterpret_cast<const u32x4*>(
          WT + (size_t)(ct * 16 + c) * DD + kk * 32 + g * 8);
      acc = __builtin_amdgcn_mfma_f32_16x16x32_bf16(
          a[kk], __builtin_bit_cast(bf16x8, bv), acc, 0, 0, 0);
    }
#pragma unroll
    for (int r = 0; r < 4; ++r)
      OUT[(size_t)(rbase + g * 4 + r) * DD + ct * 16 + c] = f2bf(acc[r] * scale);
  }
}

// ---------------------------------------------------------------------------
// Kernel 3: flash-style scores + online base-2 logsumexp partials.
// grid (NQ/256, NSPLIT).  4 waves x 64 Q-rows.  K tile [64x256] bf16
// double-buffered in LDS via global_load_lds(16) with XOR chunk-swizzle on
// the GLOBAL source (LDS dest linear); counted vmcnt(8) across the barrier.
//
// R4 lesson: __syncthreads() at tile end compiles to s_waitcnt vmcnt(0) --
// it DRAINED the prefetch issued at the top of the same iteration, exposing
// full memory latency every tile (MfmaUtil pinned ~19%).  Replaced with
// lgkmcnt(0) + raw s_barrier (read-before-overwrite hazard only); prefetch
// stays in flight, consumed by next iteration's counted vmcnt(8).
// ---------------------------------------------------------------------------
__global__ __launch_bounds__(256, 1) void scores_lse_kernel(
    const ushort_t* __restrict__ Qb, const ushort_t* __restrict__ Kb,
    float* __restrict__ pm, float* __restrict__ ps) {
  __shared__ __align__(128) char smem[2][KBLK * 512];  // 64 KB
  const int tid = threadIdx.x;
  const int w = tid >> 6, lane = tid & 63;
  const int g = lane >> 4, c = lane & 15;
  const int qw = blockIdx.x * 256 + w * 64;
  const int j0 = blockIdx.y * SEG;

  // A-frags: 4 row-tiles x 8 k-steps (128 VGPRs, resident whole kernel).
  bf16x8 a[4][8];
#pragma unroll
  for (int rt = 0; rt < 4; ++rt)
#pragma unroll
    for (int kk = 0; kk < 8; ++kk) {
      u32x4 v = *reinterpret_cast<const u32x4*>(
          Qb + (size_t)(qw + rt * 16 + c) * DD + kk * 32 + g * 8);
      a[rt][kk] = __builtin_bit_cast(bf16x8, v);
    }
  asm volatile("s_waitcnt vmcnt(0)" ::: "memory");

  float m[4][4], s[4][4];
#pragma unroll
  for (int rt = 0; rt < 4; ++rt)
#pragma unroll
    for (int r = 0; r < 4; ++r) { m[rt][r] = -3.4e38f; s[rt][r] = 0.f; }

  // stage tile t into buffer buf: LDS[row][ch] = K[row][ch^(row&7)]
#define STAGE(buf, t)                                                          \
  do {                                                                         \
    const char* kbase_ = (const char*)(Kb + (size_t)(j0 + (t) * KBLK) * DD);   \
    _Pragma("unroll") for (int i_ = 0; i_ < 8; ++i_) {                         \
      int L_ = (w * 8 + i_) * 64 + lane;                                       \
      int row_ = L_ >> 5, ch_ = L_ & 31;                                       \
      const char* src_ = kbase_ + row_ * 512 + ((ch_ ^ (row_ & 7)) * 16);      \
      char* dst_ = &smem[buf][L_ * 16];                                        \
      __builtin_amdgcn_global_load_lds((gptr_t)src_, (lptr_t)dst_, 16, 0, 0);  \
    }                                                                          \
  } while (0)

  STAGE(0, 0);  // prologue

  for (int t = 0; t < NT; ++t) {
    const int cur = t & 1;
    if (t + 1 < NT) {
      STAGE(cur ^ 1, t + 1);                              // 8 new loads in flight
      asm volatile("s_waitcnt vmcnt(8)" ::: "memory");    // tile t's 8 have landed
    } else {
      asm volatile("s_waitcnt vmcnt(0)" ::: "memory");
    }
    __builtin_amdgcn_s_barrier();

#pragma unroll
    for (int jt = 0; jt < 4; ++jt) {
      const int jr = jt * 16 + c;
      const char* bbase = &smem[cur][jr * 512];
      f32x4 acc[4];
#pragma unroll
      for (int rt = 0; rt < 4; ++rt) acc[rt] = {0.f, 0.f, 0.f, 0.f};
#pragma unroll
      for (int kk = 0; kk < 8; ++kk) {
        int ch = (kk * 4 + g) ^ (jr & 7);
        bf16x8 b = *reinterpret_cast<const bf16x8*>(bbase + ch * 16);
#pragma unroll
        for (int rt = 0; rt < 4; ++rt)
          acc[rt] = __builtin_amdgcn_mfma_f32_16x16x32_bf16(a[rt][kk], b, acc[rt], 0, 0, 0);
      }
      // fold this col-tile into the base-2 online lse (acc dies here)
#pragma unroll
      for (int rt = 0; rt < 4; ++rt)
#pragma unroll
        for (int r = 0; r < 4; ++r) {
          float v = acc[rt][r];
          float mo = m[rt][r];
          float mn = fmaxf(mo, v);
          s[rt][r] = s[rt][r] * fexp2(mo - mn) + fexp2(v - mn);
          m[rt][r] = mn;
        }
    }
    // reads of buf[cur] done (per-wave), then barrier => all waves done =>
    // next iteration's STAGE may overwrite buf[cur].  NO vmcnt drain here:
    // tile t+1's 8 loads stay in flight across both barriers.
    asm volatile("s_waitcnt lgkmcnt(0)" ::: "memory");
    __builtin_amdgcn_s_barrier();
  }
#undef STAGE

  // merge the 16 lanes of each group (each held a 4-col-stride slice)
#pragma unroll
  for (int rt = 0; rt < 4; ++rt)
#pragma unroll
    for (int r = 0; r < 4; ++r) {
      float M = m[rt][r], S = s[rt][r];
#pragma unroll
      for (int off = 1; off < 16; off <<= 1) {
        float Mo = __shfl_xor(M, off);
        float So = __shfl_xor(S, off);
        float Mn = fmaxf(M, Mo);
        S = S * fexp2(M - Mn) + So * fexp2(Mo - Mn);
        M = Mn;
      }
      if (c == 0) {
        int row = qw + rt * 16 + g * 4 + r;
        pm[blockIdx.y * NQ + row] = M;
        ps[blockIdx.y * NQ + row] = S;
      }
    }
}

// ---------------------------------------------------------------------------
// Kernel 4a: per-row lse (base-2 partials -> natural), block-sum -> part[32]
// ---------------------------------------------------------------------------
__global__ __launch_bounds__(256) void finalize1_kernel(
    const float* __restrict__ pm, const float* __restrict__ ps,
    float* __restrict__ part) {
  const int tid = threadIdx.x;
  const int row = blockIdx.x * 256 + tid;
  float M = -3.4e38f;
#pragma unroll
  for (int k = 0; k < NSPLIT; ++k) M = fmaxf(M, pm[k * NQ + row]);
  float S = 0.f;
#pragma unroll
  for (int k = 0; k < NSPLIT; ++k) S += ps[k * NQ + row] * fexp2(pm[k * NQ + row] - M);
  float v = LN2 * (M + flog2(S));

  __shared__ float red[256];
  red[tid] = v;
  __syncthreads();
#pragma unroll
  for (int st = 128; st > 0; st >>= 1) {
    if (tid < st) red[tid] += red[tid + st];
    __syncthreads();
  }
  if (tid == 0) part[blockIdx.x] = red[0];
}

// ---------------------------------------------------------------------------
// Kernel 4b: sum 32 partials, negate.
// ---------------------------------------------------------------------------
__global__ __launch_bounds__(64) void finalize2_kernel(
    const float* __restrict__ part, float* __restrict__ out) {
  const int lane = threadIdx.x;
  float v = (lane < 32) ? part[lane] : 0.f;
#pragma unroll
  for (int off = 1; off < 64; off <<= 1) v += __shfl_xor(v, off);
  if (lane == 0) out[0] = -v;
}

// ---------------------------------------------------------------------------
extern "C" void kernel_launch(void* const* d_in, const int* in_sizes, int n_in,
                              void* d_out, int out_size, void* d_ws, size_t ws_size,
                              hipStream_t stream) {
  const float* xq = (const float*)d_in[0];
  const float* xk = (const float*)d_in[1];
  const float* Wq = (const float*)d_in[2];
  const float* Wk = (const float*)d_in[3];

  char* ws = (char*)d_ws;
  // ws: Qb 4MB | Kb 4MB | WqT 128KB | WkT 128KB | pm 512KB | ps 512KB | part 128B
  ushort_t* Qb = (ushort_t*)(ws);
  ushort_t* Kb = (ushort_t*)(ws + (size_t)NQ * DD * 2);
  ushort_t* WqT = (ushort_t*)(ws + (size_t)(NQ + NK) * DD * 2);
  ushort_t* WkT = (ushort_t*)(ws + (size_t)(NQ + NK) * DD * 2 + (size_t)DD * DD * 2);
  float* pm = (float*)(ws + (size_t)(NQ + NK) * DD * 2 + (size_t)2 * DD * DD * 2);
  float* ps = pm + (size_t)NSPLIT * NQ;
  float* part = ps + (size_t)NSPLIT * NQ;

  hipLaunchKernelGGL(transpose_w_kernel, dim3(512), dim3(256), 0, stream, Wq, Wk, WqT, WkT);
  hipLaunchKernelGGL(proj_kernel, dim3(128, 2, 2), dim3(256), 0, stream,
                     xq, xk, WqT, WkT, Qb, Kb);
  hipLaunchKernelGGL(scores_lse_kernel, dim3(NQ / 256, NSPLIT), dim3(256), 0, stream,
                     Qb, Kb, pm, ps);
  hipLaunchKernelGGL(finalize1_kernel, dim3(32), dim3(256), 0, stream, pm, ps, part);
  hipLaunchKernelGGL(finalize2_kernel, dim3(1), dim3(64), 0, stream, part, (float*)d_out);
}

// Round 6
// 73.712 us; speedup vs baseline: 1.3567x; 1.3567x over previous
//
#include <hip/hip_runtime.h>

typedef unsigned short ushort_t;
typedef __attribute__((ext_vector_type(8))) __bf16 bf16x8;
typedef __attribute__((ext_vector_type(4))) float f32x4;
typedef __attribute__((ext_vector_type(4))) unsigned int u32x4;
typedef __attribute__((ext_vector_type(8))) unsigned short u16x8;

#define NQ 8192
#define NK 8192
#define DD 256
#define NSPLIT 8
#define SEG (NK / NSPLIT)   // 1024 K-rows per split
#define KBLK 64             // K rows staged in LDS per tile
#define NT (SEG / KBLK)     // 16 tiles per block
#define LOG2E 1.4426950408889634f
#define LN2 0.6931471805599453f

using gptr_t = const __attribute__((address_space(1))) void*;
using lptr_t = __attribute__((address_space(3))) void*;

__device__ __forceinline__ float fexp2(float x) { return __builtin_amdgcn_exp2f(x); }
__device__ __forceinline__ float flog2(float x) { return __builtin_amdgcn_logf(x); }

// round-to-nearest-even fp32 -> bf16
__device__ __forceinline__ ushort_t f2bf(float f) {
  unsigned int u = __builtin_bit_cast(unsigned int, f);
  unsigned int r = 0x7FFFu + ((u >> 16) & 1u);
  return (ushort_t)((u + r) >> 16);
}

// ---------------------------------------------------------------------------
// Kernel 1: W [256x256] fp32 -> W^T bf16
// ---------------------------------------------------------------------------
__global__ __launch_bounds__(256) void transpose_w_kernel(
    const float* __restrict__ Wq, const float* __restrict__ Wk,
    ushort_t* __restrict__ WqT, ushort_t* __restrict__ WkT) {
  int idx = blockIdx.x * 256 + threadIdx.x;
  const float* W = (idx < 65536) ? Wq : Wk;
  ushort_t* WT = (idx < 65536) ? WqT : WkT;
  int e = idx & 65535;
  int d = e >> 8, n = e & 255;
  WT[n * 256 + d] = f2bf(W[d * 256 + n]);
}

// ---------------------------------------------------------------------------
// Kernel 2: projections  OUT_bf16[8192x256] = X_fp32 @ W  (via W^T rows)
// Q additionally scaled by log2(e) so the lse runs in base-2 (v_exp native).
// grid (128, 2, 2): y -> Q/K, z -> col-tile half.
// ---------------------------------------------------------------------------
__global__ __launch_bounds__(256) void proj_kernel(
    const float* __restrict__ xq, const float* __restrict__ xk,
    const ushort_t* __restrict__ WqT, const ushort_t* __restrict__ WkT,
    ushort_t* __restrict__ Qb, ushort_t* __restrict__ Kb) {
  const float* X = (blockIdx.y == 0) ? xq : xk;
  const ushort_t* WT = (blockIdx.y == 0) ? WqT : WkT;
  ushort_t* OUT = (blockIdx.y == 0) ? Qb : Kb;
  const float scale = (blockIdx.y == 0) ? LOG2E : 1.0f;

  const int tid = threadIdx.x;
  const int w = tid >> 6, lane = tid & 63;
  const int g = lane >> 4, c = lane & 15;
  const int rbase = blockIdx.x * 64 + w * 16;
  const int ctbase = blockIdx.z * 8;

  bf16x8 a[8];
#pragma unroll
  for (int kk = 0; kk < 8; ++kk) {
    const f32x4* px =
        reinterpret_cast<const f32x4*>(X + (size_t)(rbase + c) * DD + kk * 32 + g * 8);
    f32x4 x0 = px[0], x1 = px[1];
    u16x8 v;
#pragma unroll
    for (int j = 0; j < 4; ++j) { v[j] = f2bf(x0[j]); v[4 + j] = f2bf(x1[j]); }
    a[kk] = __builtin_bit_cast(bf16x8, v);
  }

#pragma unroll
  for (int ct0 = 0; ct0 < 8; ++ct0) {
    int ct = ctbase + ct0;
    f32x4 acc = {0.f, 0.f, 0.f, 0.f};
#pragma unroll
    for (int kk = 0; kk < 8; ++kk) {
      u32x4 bv = *reinterpret_cast<const u32x4*>(
          WT + (size_t)(ct * 16 + c) * DD + kk * 32 + g * 8);
      acc = __builtin_amdgcn_mfma_f32_16x16x32_bf16(
          a[kk], __builtin_bit_cast(bf16x8, bv), acc, 0, 0, 0);
    }
#pragma unroll
    for (int r = 0; r < 4; ++r)
      OUT[(size_t)(rbase + g * 4 + r) * DD + ct * 16 + c] = f2bf(acc[r] * scale);
  }
}

// ---------------------------------------------------------------------------
// Kernel 3: flash-style scores + online base-2 logsumexp partials.
// grid (NQ/128, NSPLIT).  4 waves x 32 Q-rows each (rt=2).  K tile [64x256]
// bf16 double-buffered in LDS via global_load_lds(16), XOR chunk-swizzle on
// the GLOBAL source (LDS dest linear), counted vmcnt(8), raw barriers (no
// vmcnt drain in-loop).
//
// R5 lesson: rt=4 demanded >256 regs/wave -> 1 wave/SIMD (Occupancy 10%),
// serializing MFMA-issue + VALU-issue + all latency in one wave.  rt=2 +
// (256,2) => ~140 regs, 2 blocks/CU, 2 waves/SIMD co-issue.
// Fold cost cut via grouped defer-max: rescale only when a tile's 4-score
// max exceeds the running max (~H(16)~3 times per chain in 16 tiles).
// ---------------------------------------------------------------------------
__global__ __launch_bounds__(256, 2) void scores_lse_kernel(
    const ushort_t* __restrict__ Qb, const ushort_t* __restrict__ Kb,
    float* __restrict__ pm, float* __restrict__ ps) {
  __shared__ __align__(128) char smem[2][KBLK * 512];  // 64 KB
  const int tid = threadIdx.x;
  const int w = tid >> 6, lane = tid & 63;
  const int g = lane >> 4, c = lane & 15;
  const int qw = blockIdx.x * 128 + w * 32;
  const int j0 = blockIdx.y * SEG;

  // A-frags: 2 row-tiles x 8 k-steps (64 VGPRs, resident whole kernel).
  bf16x8 a[2][8];
#pragma unroll
  for (int rt = 0; rt < 2; ++rt)
#pragma unroll
    for (int kk = 0; kk < 8; ++kk) {
      u32x4 v = *reinterpret_cast<const u32x4*>(
          Qb + (size_t)(qw + rt * 16 + c) * DD + kk * 32 + g * 8);
      a[rt][kk] = __builtin_bit_cast(bf16x8, v);
    }
  asm volatile("s_waitcnt vmcnt(0)" ::: "memory");

  float m[2][4], s[2][4];
#pragma unroll
  for (int rt = 0; rt < 2; ++rt)
#pragma unroll
    for (int r = 0; r < 4; ++r) { m[rt][r] = -3.4e38f; s[rt][r] = 0.f; }

  // stage tile t into buffer buf: LDS[row][ch] = K[row][ch^(row&7)]
#define STAGE(buf, t)                                                          \
  do {                                                                         \
    const char* kbase_ = (const char*)(Kb + (size_t)(j0 + (t) * KBLK) * DD);   \
    _Pragma("unroll") for (int i_ = 0; i_ < 8; ++i_) {                         \
      int L_ = (w * 8 + i_) * 64 + lane;                                       \
      int row_ = L_ >> 5, ch_ = L_ & 31;                                       \
      const char* src_ = kbase_ + row_ * 512 + ((ch_ ^ (row_ & 7)) * 16);      \
      char* dst_ = &smem[buf][L_ * 16];                                        \
      __builtin_amdgcn_global_load_lds((gptr_t)src_, (lptr_t)dst_, 16, 0, 0);  \
    }                                                                          \
  } while (0)

  STAGE(0, 0);  // prologue

  for (int t = 0; t < NT; ++t) {
    const int cur = t & 1;
    if (t + 1 < NT) {
      STAGE(cur ^ 1, t + 1);                              // 8 new loads in flight
      asm volatile("s_waitcnt vmcnt(8)" ::: "memory");    // tile t's 8 have landed
    } else {
      asm volatile("s_waitcnt vmcnt(0)" ::: "memory");
    }
    __builtin_amdgcn_s_barrier();

    f32x4 acc[2][4];
#pragma unroll
    for (int rt = 0; rt < 2; ++rt)
#pragma unroll
      for (int jt = 0; jt < 4; ++jt) acc[rt][jt] = {0.f, 0.f, 0.f, 0.f};

#pragma unroll
    for (int kk = 0; kk < 8; ++kk) {
#pragma unroll
      for (int jt = 0; jt < 4; ++jt) {
        int jr = jt * 16 + c;
        int ch = (kk * 4 + g) ^ (jr & 7);
        bf16x8 b = *reinterpret_cast<const bf16x8*>(&smem[cur][jr * 512 + ch * 16]);
        acc[0][jt] = __builtin_amdgcn_mfma_f32_16x16x32_bf16(a[0][kk], b, acc[0][jt], 0, 0, 0);
        acc[1][jt] = __builtin_amdgcn_mfma_f32_16x16x32_bf16(a[1][kk], b, acc[1][jt], 0, 0, 0);
      }
    }
    // reads of buf[cur] done (per-wave), then barrier => all waves done =>
    // next iteration's STAGE may overwrite buf[cur].  NO vmcnt drain here.
    asm volatile("s_waitcnt lgkmcnt(0)" ::: "memory");
    __builtin_amdgcn_s_barrier();

    // grouped defer-max fold: 4 scores per (rt,r) chain; rescale only on a
    // new running max (rare after warm-up).
#pragma unroll
    for (int rt = 0; rt < 2; ++rt)
#pragma unroll
      for (int r = 0; r < 4; ++r) {
        float v0 = acc[rt][0][r], v1 = acc[rt][1][r];
        float v2 = acc[rt][2][r], v3 = acc[rt][3][r];
        float tmax = fmaxf(fmaxf(v0, v1), fmaxf(v2, v3));
        float mo = m[rt][r];
        if (tmax > mo) {
          s[rt][r] *= fexp2(mo - tmax);
          m[rt][r] = tmax;
          mo = tmax;
        }
        s[rt][r] += fexp2(v0 - mo) + fexp2(v1 - mo) + fexp2(v2 - mo) + fexp2(v3 - mo);
      }
  }
#undef STAGE

  // merge the 16 lanes of each group (each held a 4-col-stride slice)
#pragma unroll
  for (int rt = 0; rt < 2; ++rt)
#pragma unroll
    for (int r = 0; r < 4; ++r) {
      float M = m[rt][r], S = s[rt][r];
#pragma unroll
      for (int off = 1; off < 16; off <<= 1) {
        float Mo = __shfl_xor(M, off);
        float So = __shfl_xor(S, off);
        float Mn = fmaxf(M, Mo);
        S = S * fexp2(M - Mn) + So * fexp2(Mo - Mn);
        M = Mn;
      }
      if (c == 0) {
        int row = qw + rt * 16 + g * 4 + r;
        pm[blockIdx.y * NQ + row] = M;
        ps[blockIdx.y * NQ + row] = S;
      }
    }
}

// ---------------------------------------------------------------------------
// Kernel 4a: per-row lse (base-2 partials -> natural), block-sum -> part[32]
// ---------------------------------------------------------------------------
__global__ __launch_bounds__(256) void finalize1_kernel(
    const float* __restrict__ pm, const float* __restrict__ ps,
    float* __restrict__ part) {
  const int tid = threadIdx.x;
  const int row = blockIdx.x * 256 + tid;
  float M = -3.4e38f;
#pragma unroll
  for (int k = 0; k < NSPLIT; ++k) M = fmaxf(M, pm[k * NQ + row]);
  float S = 0.f;
#pragma unroll
  for (int k = 0; k < NSPLIT; ++k) S += ps[k * NQ + row] * fexp2(pm[k * NQ + row] - M);
  float v = LN2 * (M + flog2(S));

  __shared__ float red[256];
  red[tid] = v;
  __syncthreads();
#pragma unroll
  for (int st = 128; st > 0; st >>= 1) {
    if (tid < st) red[tid] += red[tid + st];
    __syncthreads();
  }
  if (tid == 0) part[blockIdx.x] = red[0];
}

// ---------------------------------------------------------------------------
// Kernel 4b: sum 32 partials, negate.
// ---------------------------------------------------------------------------
__global__ __launch_bounds__(64) void finalize2_kernel(
    const float* __restrict__ part, float* __restrict__ out) {
  const int lane = threadIdx.x;
  float v = (lane < 32) ? part[lane] : 0.f;
#pragma unroll
  for (int off = 1; off < 64; off <<= 1) v += __shfl_xor(v, off);
  if (lane == 0) out[0] = -v;
}

// ---------------------------------------------------------------------------
extern "C" void kernel_launch(void* const* d_in, const int* in_sizes, int n_in,
                              void* d_out, int out_size, void* d_ws, size_t ws_size,
                              hipStream_t stream) {
  const float* xq = (const float*)d_in[0];
  const float* xk = (const float*)d_in[1];
  const float* Wq = (const float*)d_in[2];
  const float* Wk = (const float*)d_in[3];

  char* ws = (char*)d_ws;
  // ws: Qb 4MB | Kb 4MB | WqT 128KB | WkT 128KB | pm 256KB | ps 256KB | part 128B
  ushort_t* Qb = (ushort_t*)(ws);
  ushort_t* Kb = (ushort_t*)(ws + (size_t)NQ * DD * 2);
  ushort_t* WqT = (ushort_t*)(ws + (size_t)(NQ + NK) * DD * 2);
  ushort_t* WkT = (ushort_t*)(ws + (size_t)(NQ + NK) * DD * 2 + (size_t)DD * DD * 2);
  float* pm = (float*)(ws + (size_t)(NQ + NK) * DD * 2 + (size_t)2 * DD * DD * 2);
  float* ps = pm + (size_t)NSPLIT * NQ;
  float* part = ps + (size_t)NSPLIT * NQ;

  hipLaunchKernelGGL(transpose_w_kernel, dim3(512), dim3(256), 0, stream, Wq, Wk, WqT, WkT);
  hipLaunchKernelGGL(proj_kernel, dim3(128, 2, 2), dim3(256), 0, stream,
                     xq, xk, WqT, WkT, Qb, Kb);
  hipLaunchKernelGGL(scores_lse_kernel, dim3(NQ / 128, NSPLIT), dim3(256), 0, stream,
                     Qb, Kb, pm, ps);
  hipLaunchKernelGGL(finalize1_kernel, dim3(32), dim3(256), 0, stream, pm, ps, part);
  hipLaunchKernelGGL(finalize2_kernel, dim3(1), dim3(64), 0, stream, part, (float*)d_out);
}